// Round 10
// baseline (217.310 us; speedup 1.0000x reference)
//
#include <hip/hip_runtime.h>

typedef __attribute__((ext_vector_type(8))) short short8;
typedef __attribute__((ext_vector_type(4))) float f32x4;

// ---------- helpers ----------
__device__ __forceinline__ unsigned short f2bf(float f) {
  unsigned u = __float_as_uint(f);
  u += 0x7fffu + ((u >> 16) & 1u);   // round-to-nearest-even
  return (unsigned short)(u >> 16);
}
__device__ __forceinline__ float bf2f(unsigned short h) {
  return __uint_as_float(((unsigned)h) << 16);
}
// pack two f32 -> one dword of 2 bf16 (RNE), single instruction
__device__ __forceinline__ unsigned pk_bf16(float lo, float hi) {
  unsigned r;
  asm("v_cvt_pk_bf16_f32 %0, %1, %2" : "=v"(r) : "v"(lo), "v"(hi));
  return r;
}
// tanh-approx GELU, ~9 VALU + 2 trans
__device__ __forceinline__ float gelu_f(float v) {
  const float t = v * v;
  const float w = fmaf(0.0356774081f, t, 0.7978845608f);
  const float u = v * w;
  const float e = __expf(u + u);
  const float d = e + 1.0f;
  const float r = __builtin_amdgcn_rcpf(d);
  const float th = fmaf(-2.0f, r, 1.0f);
  const float h = 0.5f * v;
  return fmaf(h, th, h);
}
__device__ __forceinline__ void gload16(const void* g, void* l) {
  __builtin_amdgcn_global_load_lds((const __attribute__((address_space(1))) void*)g,
                                   (__attribute__((address_space(3))) void*)l, 16, 0, 0);
}

// T4 counted-vmcnt barriers: WAIT8_BAR waits only the OLDEST 8 loads (the
// buffer about to be consumed), leaving the newer prefetch in flight across
// the whole compute phase. DRAIN_BAR (vmcnt 0) only at tail.
#define WAIT8_BAR { asm volatile("s_waitcnt vmcnt(8)" ::: "memory"); \
                    __builtin_amdgcn_s_barrier();                     \
                    asm volatile("" ::: "memory"); }
#define BAR_ONLY  { __builtin_amdgcn_s_barrier();                     \
                    asm volatile("" ::: "memory"); }
#define DRAIN_BAR { asm volatile("s_waitcnt vmcnt(0)" ::: "memory"); \
                    __builtin_amdgcn_s_barrier();                     \
                    asm volatile("" ::: "memory"); }

// ---------- kernel 1: grouped 3x3 conv + bias + GELU (register-blocked, PROVEN R3) ----------
// x: [8,12,1024,64] f32.  Outputs (bf16 bits as ushort):
//   qb,kb: [8,48,1024,64]   vtb: [8,3072,1024] (transposed for PV B-operand)
__global__ __launch_bounds__(256) void conv_qkv_kernel(
    const float* __restrict__ x,
    const float* __restrict__ wq, const float* __restrict__ bq,
    const float* __restrict__ wk, const float* __restrict__ bk,
    const float* __restrict__ wv, const float* __restrict__ bv,
    unsigned short* __restrict__ qb, unsigned short* __restrict__ kb,
    unsigned short* __restrict__ vtb) {
  __shared__ float sin_[66][68];
  const int tid = threadIdx.x;
  const int b = blockIdx.z, g = blockIdx.y;
  const int s0 = blockIdx.x << 6;
  const float* xp = x + ((size_t)(b * 12 + g) << 16);
  for (int i = tid; i < 66 * 64; i += 256) {
    const int r = i >> 6, n = i & 63;
    const int s = s0 - 1 + r;
    sin_[r][n + 1] = (s >= 0 && s < 1024) ? xp[(s << 6) + n] : 0.0f;
  }
  if (tid < 66) { sin_[tid][0] = 0.0f; sin_[tid][65] = 0.0f; sin_[tid][66] = 0.0f; sin_[tid][67] = 0.0f; }
  __syncthreads();

  // ---- pass 1 (q & k): thread owns 4 rows x 4 cols; rolling 3-row window ----
  {
    const int n0 = (tid & 15) << 2;
    const int rb = (tid >> 4) << 2;
    float W[8][9], Bi[8];
#pragma unroll
    for (int j = 0; j < 4; ++j) {
      const int oc = (g << 2) + j;
#pragma unroll
      for (int t = 0; t < 9; ++t) { W[j][t] = wq[oc * 9 + t]; W[4 + j][t] = wk[oc * 9 + t]; }
      Bi[j] = bq[oc]; Bi[4 + j] = bk[oc];
    }
    float rA[6], rB[6], rC[6];
#define LDROW(dst, ridx)                                                              \
    { const float4 p0 = *reinterpret_cast<const float4*>(&sin_[ridx][n0]);            \
      const float2 p1 = *reinterpret_cast<const float2*>(&sin_[ridx][n0 + 4]);        \
      dst[0] = p0.x; dst[1] = p0.y; dst[2] = p0.z; dst[3] = p0.w;                     \
      dst[4] = p1.x; dst[5] = p1.y; }
    LDROW(rA, rb)
    LDROW(rB, rb + 1)
#pragma unroll
    for (int i = 0; i < 4; ++i) {
      const int s = rb + i;
      LDROW(rC, s + 2)
      float pa[8][4];
#pragma unroll
      for (int j = 0; j < 8; ++j)
#pragma unroll
        for (int q = 0; q < 4; ++q) {
          float a = Bi[j];
#pragma unroll
          for (int dc = 0; dc < 3; ++dc) {
            a = fmaf(W[j][dc], rA[q + dc], a);
            a = fmaf(W[j][3 + dc], rB[q + dc], a);
            a = fmaf(W[j][6 + dc], rC[q + dc], a);
          }
          pa[j][q] = a;
        }
#pragma unroll
      for (int j = 0; j < 8; ++j)
#pragma unroll
        for (int q = 0; q < 4; ++q) pa[j][q] = gelu_f(pa[j][q]);
#pragma unroll
      for (int j = 0; j < 8; ++j) {
        const int oc = (g << 2) + (j & 3);
        unsigned short* dst = (j < 4) ? qb : kb;
        uint2 pk;
        pk.x = pk_bf16(pa[j][0], pa[j][1]);
        pk.y = pk_bf16(pa[j][2], pa[j][3]);
        *reinterpret_cast<uint2*>(dst + (((b * 48 + oc) << 16) + ((s0 + s) << 6) + n0)) = pk;
      }
#pragma unroll
      for (int c = 0; c < 6; ++c) { rA[c] = rB[c]; rB[c] = rC[c]; }
    }
#undef LDROW
  }

  // ---- pass 2 (v, transposed out): thread owns 2 rows (s-pair) x 8 cols ----
  {
    const int sp = (tid & 31) << 1;
    const int nb = (tid >> 5) << 3;
    float W[4][9], Bi[4];
#pragma unroll
    for (int j = 0; j < 4; ++j) {
      const int oc = (g << 2) + j;
#pragma unroll
      for (int t = 0; t < 9; ++t) W[j][t] = wv[oc * 9 + t];
      Bi[j] = bv[oc];
    }
    float c0[4], c1[4], c2[4];
#pragma unroll
    for (int r = 0; r < 4; ++r) { c0[r] = sin_[sp + r][nb]; c1[r] = sin_[sp + r][nb + 1]; }
#pragma unroll
    for (int i = 0; i < 8; ++i) {
      const int n = nb + i;
#pragma unroll
      for (int r = 0; r < 4; ++r) c2[r] = sin_[sp + r][n + 2];
      float pa[4][2];
#pragma unroll
      for (int j = 0; j < 4; ++j)
#pragma unroll
        for (int ss = 0; ss < 2; ++ss) {
          float a = Bi[j];
#pragma unroll
          for (int dr = 0; dr < 3; ++dr) {
            a = fmaf(W[j][dr * 3 + 0], c0[ss + dr], a);
            a = fmaf(W[j][dr * 3 + 1], c1[ss + dr], a);
            a = fmaf(W[j][dr * 3 + 2], c2[ss + dr], a);
          }
          pa[j][ss] = a;
        }
#pragma unroll
      for (int j = 0; j < 4; ++j)
#pragma unroll
        for (int ss = 0; ss < 2; ++ss) pa[j][ss] = gelu_f(pa[j][ss]);
#pragma unroll
      for (int j = 0; j < 4; ++j) {
        const size_t d = (size_t)b * 3072 + ((((g << 2) + j) << 6) + n);
        *reinterpret_cast<unsigned*>(vtb + ((d << 10) + s0 + sp)) = pk_bf16(pa[j][0], pa[j][1]);
      }
#pragma unroll
      for (int r = 0; r < 4; ++r) { c0[r] = c1[r]; c1[r] = c2[r]; }
    }
  }
}

// ---------- GEMM tile macros (shared by qk/pv) ----------
// LDS tile [128][64] bf16, XOR-swizzled col-blocks (T2, both-sides). T5 setprio
// wraps the compute cluster.
#define GEMM_COMPUTE(A_, B_) {                                                          \
    __builtin_amdgcn_s_setprio(1);                                                      \
    _Pragma("unroll")                                                                   \
    for (int kk = 0; kk < 2; ++kk) {                                                    \
      const int pos = ((((kk << 2) + lhi) ^ (l15 & 7)) << 3);                           \
      short8 aF[4], bF[4];                                                              \
      _Pragma("unroll")                                                                 \
      for (int m = 0; m < 4; ++m)                                                       \
        aF[m] = *reinterpret_cast<const short8*>(&(A_)[(((wm << 6) + (m << 4) + l15) << 6) + pos]); \
      _Pragma("unroll")                                                                 \
      for (int n = 0; n < 4; ++n)                                                       \
        bF[n] = *reinterpret_cast<const short8*>(&(B_)[(((wn << 6) + (n << 4) + l15) << 6) + pos]); \
      _Pragma("unroll")                                                                 \
      for (int m = 0; m < 4; ++m)                                                       \
        _Pragma("unroll")                                                               \
        for (int n = 0; n < 4; ++n)                                                     \
          acc[m][n] = __builtin_amdgcn_mfma_f32_16x16x32_bf16(aF[m], bF[n], acc[m][n], 0, 0, 0); \
    }                                                                                   \
    __builtin_amdgcn_s_setprio(0); }

// ---------- kernel 2: score = (Q K^T)/sqrt(768), fp32 out ----------
// q,k: [8,48,1024,64] bf16.  score: [8,1024,1024] f32.
// 2-buffer, 2-DEEP counted-vmcnt pipeline (T3+T4): stage t+2 after computing t;
// wait vmcnt(8) = oldest buffer only. Loads get ~2 compute phases to land.
__global__ __launch_bounds__(256) void qk_kernel(
    const unsigned short* __restrict__ q, const unsigned short* __restrict__ k,
    float* __restrict__ score) {
  __shared__ __align__(16) unsigned short As0[128 * 64], As1[128 * 64];
  __shared__ __align__(16) unsigned short Bs0[128 * 64], Bs1[128 * 64];
  const int tid = threadIdx.x;
  const int w = tid >> 6, lane = tid & 63;
  const int b = blockIdx.z;
  const int s0 = blockIdx.y << 7, t0 = blockIdx.x << 7;
  const int wm = w >> 1, wn = w & 1;
  const int l15 = lane & 15, lhi = lane >> 4;
  const int srow = lane >> 3;           // row within 8-row stage group
  const int scb = (lane & 7) ^ srow;    // pre-swizzled source col-block
  f32x4 acc[4][4] = {};

  const unsigned short* qbase = q + ((b * 48) << 16) + (s0 << 6);
  const unsigned short* kbase = k + ((b * 48) << 16) + (t0 << 6);

#define QK_STAGE(cs, A_, B_) {                                        \
    const unsigned short* qa = qbase + ((cs) << 16);                  \
    const unsigned short* ka = kbase + ((cs) << 16);                  \
    _Pragma("unroll")                                                 \
    for (int i = 0; i < 4; ++i) {                                     \
      const int fe = ((((i * 4 + w) << 3) + srow) << 6) + (scb << 3); \
      const int lb = (i * 4 + w) << 10;                               \
      gload16(qa + fe, (char*)(A_) + lb);                             \
      gload16(ka + fe, (char*)(B_) + lb);                             \
    } }

  QK_STAGE(0, As0, Bs0)     // 8 loads in flight
  QK_STAGE(1, As1, Bs1)     // 16 in flight
  for (int c2 = 0; c2 < 23; ++c2) {
    const int c0 = c2 << 1;
    WAIT8_BAR                           // buffer c0 landed; c0+1 still flying
    GEMM_COMPUTE(As0, Bs0)
    BAR_ONLY                            // all waves done reading As0/Bs0
    QK_STAGE(c0 + 2, As0, Bs0)
    WAIT8_BAR                           // buffer c0+1 landed; c0+2 flying
    GEMM_COMPUTE(As1, Bs1)
    BAR_ONLY
    QK_STAGE(c0 + 3, As1, Bs1)
  }
  WAIT8_BAR                             // t=46 (As0); 47 still flying
  GEMM_COMPUTE(As0, Bs0)
  DRAIN_BAR                             // t=47: full drain (vmcnt(8) would no-op)
  GEMM_COMPUTE(As1, Bs1)
#undef QK_STAGE
  const float scale = 0.03608439182435161f;  // 1/sqrt(768)
#pragma unroll
  for (int m = 0; m < 4; ++m) {
    const int row = (wm << 6) + (m << 4) + (lhi << 2);
#pragma unroll
    for (int n = 0; n < 4; ++n) {
      const int col = (wn << 6) + (n << 4) + l15;
      float* op = score + ((size_t)((b << 10) + s0 + row) << 10) + t0 + col;
#pragma unroll
      for (int r = 0; r < 4; ++r) op[(size_t)r << 10] = acc[m][n][r] * scale;
    }
  }
}

// ---------- kernel 3: row softmax, fp32 in, bf16 out ----------
__global__ __launch_bounds__(256) void softmax_kernel(
    const float* __restrict__ score, unsigned short* __restrict__ p) {
  __shared__ float redm[4], reds[4];
  const int row = blockIdx.x;
  const int tid = threadIdx.x;
  const int w = tid >> 6, lane = tid & 63;
  const float* sr = score + ((size_t)row << 10);
  const float4 v = reinterpret_cast<const float4*>(sr)[tid];
  float mx = fmaxf(fmaxf(v.x, v.y), fmaxf(v.z, v.w));
#pragma unroll
  for (int o = 1; o < 64; o <<= 1) mx = fmaxf(mx, __shfl_xor(mx, o));
  if (lane == 0) redm[w] = mx;
  __syncthreads();
  mx = fmaxf(fmaxf(redm[0], redm[1]), fmaxf(redm[2], redm[3]));
  const float e0 = __expf(v.x - mx), e1 = __expf(v.y - mx);
  const float e2 = __expf(v.z - mx), e3 = __expf(v.w - mx);
  float s = e0 + e1 + e2 + e3;
#pragma unroll
  for (int o = 1; o < 64; o <<= 1) s += __shfl_xor(s, o);
  if (lane == 0) reds[w] = s;
  __syncthreads();
  s = reds[0] + reds[1] + reds[2] + reds[3];
  const float inv = 1.0f / s;
  uint2 pk;
  pk.x = pk_bf16(e0 * inv, e1 * inv);
  pk.y = pk_bf16(e2 * inv, e3 * inv);
  *reinterpret_cast<uint2*>(&p[((size_t)row << 10) + (tid << 2)]) = pk;
}

// ---------- kernel 4: O = P @ V2  (per batch 1024x3072x1024) ----------
// p: [8,1024,1024] bf16; vt: [8,3072,1024] bf16; o2: [8,1024,3072] bf16
// Same 2-deep counted-vmcnt pipeline; grid (24,8,8).
__global__ __launch_bounds__(256) void pv_kernel(
    const unsigned short* __restrict__ p, const unsigned short* __restrict__ vt,
    unsigned short* __restrict__ o2) {
  __shared__ __align__(16) unsigned short As0[128 * 64], As1[128 * 64];
  __shared__ __align__(16) unsigned short Bs0[128 * 64], Bs1[128 * 64];
  const int tid = threadIdx.x;
  const int w = tid >> 6, lane = tid & 63;
  const int b = blockIdx.z;
  const int s0 = blockIdx.y << 7, d0 = blockIdx.x << 7;
  const int wm = w >> 1, wn = w & 1;
  const int l15 = lane & 15, lhi = lane >> 4;
  const int srow = lane >> 3;
  const int scb = (lane & 7) ^ srow;
  f32x4 acc[4][4] = {};

  const unsigned short* pbase = p + ((size_t)(b << 10) << 10);
  const unsigned short* vbase = vt + ((size_t)(b * 3072 + d0) << 10);

#define PV_STAGE(t0k, A_, B_) {                                          \
    _Pragma("unroll")                                                    \
    for (int i = 0; i < 4; ++i) {                                        \
      const int rr = ((i * 4 + w) << 3) + srow;                          \
      const int cc = (t0k) + (scb << 3);                                 \
      const int lb = (i * 4 + w) << 10;                                  \
      gload16(pbase + ((size_t)(s0 + rr) << 10) + cc, (char*)(A_) + lb); \
      gload16(vbase + ((size_t)rr << 10) + cc, (char*)(B_) + lb);        \
    } }

  PV_STAGE(0, As0, Bs0)
  PV_STAGE(64, As1, Bs1)
  for (int c2 = 0; c2 < 7; ++c2) {
    const int t0k = c2 << 7;
    WAIT8_BAR
    GEMM_COMPUTE(As0, Bs0)
    BAR_ONLY
    PV_STAGE(t0k + 128, As0, Bs0)
    WAIT8_BAR
    GEMM_COMPUTE(As1, Bs1)
    BAR_ONLY
    PV_STAGE(t0k + 192, As1, Bs1)
  }
  WAIT8_BAR                  // k=896 tile (As0); 960 still flying
  GEMM_COMPUTE(As0, Bs0)
  DRAIN_BAR                  // k=960: full drain
  GEMM_COMPUTE(As1, Bs1)
#undef PV_STAGE
#pragma unroll
  for (int m = 0; m < 4; ++m) {
    const int row = (wm << 6) + (m << 4) + (lhi << 2);
#pragma unroll
    for (int n = 0; n < 4; ++n) {
      const int col = (wn << 6) + (n << 4) + l15;
      unsigned short* op = o2 + ((size_t)((b << 10) + s0 + row)) * 3072 + d0 + col;
#pragma unroll
      for (int r = 0; r < 4; ++r) op[(size_t)r * 3072] = f2bf(acc[m][n][r]);
    }
  }
}

// ---------- kernel 5: 1x1 conv (48->12) + LayerNorm(64) + residual ----------
__global__ __launch_bounds__(256) void out_kernel(
    const unsigned short* __restrict__ o2, const float* __restrict__ x,
    const float* __restrict__ w1, const float* __restrict__ b1,
    const float* __restrict__ lnw, const float* __restrict__ lnb,
    float* __restrict__ out) {
  const int tid = threadIdx.x;
  const int w = tid >> 6, lane = tid & 63;
  const int row = (blockIdx.x << 2) + w;      // b*1024 + s
  const int b = row >> 10, s = row & 1023;
  const unsigned short* op = o2 + (size_t)row * 3072 + lane;
  float ov[48];
#pragma unroll
  for (int c = 0; c < 48; ++c) ov[c] = bf2f(op[c << 6]);
  float acc[12];
#pragma unroll
  for (int m = 0; m < 12; ++m) {
    float a = b1[m];
#pragma unroll
    for (int c = 0; c < 48; ++c) a = fmaf(ov[c], w1[m * 48 + c], a);
    acc[m] = a;
  }
  const float wn_ = lnw[lane], bn_ = lnb[lane];
#pragma unroll
  for (int m = 0; m < 12; ++m) {
    float s1 = acc[m], s2 = acc[m] * acc[m];
#pragma unroll
    for (int o = 1; o < 64; o <<= 1) { s1 += __shfl_xor(s1, o); s2 += __shfl_xor(s2, o); }
    const float mu = s1 * 0.015625f;
    const float var = s2 * 0.015625f - mu * mu;
    const float rs = rsqrtf(var + 1e-5f);
    const size_t xi = ((size_t)(b * 12 + m) << 16) + (s << 6) + lane;
    out[xi] = (acc[m] - mu) * rs * wn_ + bn_ + x[xi];
  }
}

// ---------- launch ----------
extern "C" void kernel_launch(void* const* d_in, const int* in_sizes, int n_in,
                              void* d_out, int out_size, void* d_ws, size_t ws_size,
                              hipStream_t stream) {
  (void)in_sizes; (void)n_in; (void)out_size; (void)ws_size;
  const float* x   = (const float*)d_in[0];
  const float* wq  = (const float*)d_in[1];
  const float* bq  = (const float*)d_in[2];
  const float* wk  = (const float*)d_in[3];
  const float* bk  = (const float*)d_in[4];
  const float* wv  = (const float*)d_in[5];
  const float* bv  = (const float*)d_in[6];
  const float* w1  = (const float*)d_in[7];
  const float* b1  = (const float*)d_in[8];
  const float* lnw = (const float*)d_in[9];
  const float* lnb = (const float*)d_in[10];

  char* ws = (char*)d_ws;
  unsigned short* qb  = (unsigned short*)(ws);              // 50331648 B
  unsigned short* kb  = (unsigned short*)(ws + 50331648);   // 50331648 B
  unsigned short* vtb = (unsigned short*)(ws + 100663296);  // 50331648 B
  float*          sc  = (float*)(ws + 150994944);           // 33554432 B
  unsigned short* pb  = (unsigned short*)(ws + 184549376);  // 16777216 B  (total 192 MiB)
  unsigned short* o2b = (unsigned short*)(ws);              // reuse q region (dead after qk)
  float* outp = (float*)d_out;

  conv_qkv_kernel<<<dim3(16, 12, 8), 256, 0, stream>>>(x, wq, bq, wk, bk, wv, bv, qb, kb, vtb);
  qk_kernel<<<dim3(8, 8, 8), 256, 0, stream>>>(qb, kb, sc);
  softmax_kernel<<<dim3(8192), 256, 0, stream>>>(sc, pb);
  pv_kernel<<<dim3(24, 8, 8), 256, 0, stream>>>(pb, vtb, o2b);
  out_kernel<<<dim3(2048), 256, 0, stream>>>(o2b, x, w1, b1, lnw, lnb, outp);
}

// Round 11
// 211.801 us; speedup vs baseline: 1.0260x; 1.0260x over previous
//
#include <hip/hip_runtime.h>

typedef __attribute__((ext_vector_type(8))) short short8;
typedef __attribute__((ext_vector_type(4))) float f32x4;

// ---------- helpers ----------
__device__ __forceinline__ unsigned short f2bf(float f) {
  unsigned u = __float_as_uint(f);
  u += 0x7fffu + ((u >> 16) & 1u);   // round-to-nearest-even
  return (unsigned short)(u >> 16);
}
__device__ __forceinline__ float bf2f(unsigned short h) {
  return __uint_as_float(((unsigned)h) << 16);
}
// pack two f32 -> one dword of 2 bf16 (RNE), single instruction
__device__ __forceinline__ unsigned pk_bf16(float lo, float hi) {
  unsigned r;
  asm("v_cvt_pk_bf16_f32 %0, %1, %2" : "=v"(r) : "v"(lo), "v"(hi));
  return r;
}
// raw v_exp_f32 (2^x); CDNA VALU is hardware-interlocked -> safe in inline asm
__device__ __forceinline__ float exp2_raw(float x) {
  float r;
  asm("v_exp_f32 %0, %1" : "=v"(r) : "v"(x));
  return r;
}
// tanh-approx GELU (scalar form, for pass-less uses)
__device__ __forceinline__ float gelu_f(float v) {
  const float u = v * fmaf(0.10294373f, v * v, 2.3022077f);  // 2*log2(e) folded
  const float r = __builtin_amdgcn_rcpf(exp2_raw(u) + 1.0f);
  return fmaf(-v, r, v);   // v * e/(e+1)
}
__device__ __forceinline__ void gload16(const void* g, void* l) {
  __builtin_amdgcn_global_load_lds((const __attribute__((address_space(1))) void*)g,
                                   (__attribute__((address_space(3))) void*)l, 16, 0, 0);
}

// drain prefetch loads, then raw barrier (one per K-tile; compiler fences via "memory")
#define DRAIN_BAR { asm volatile("s_waitcnt vmcnt(0)" ::: "memory"); \
                    __builtin_amdgcn_s_barrier();                     \
                    asm volatile("" ::: "memory"); }

// ---------- kernel 1: grouped 3x3 conv + bias + GELU (register-blocked) ----------
// x: [8,12,1024,64] f32.  Outputs (bf16 bits as ushort):
//   qb,kb: [8,48,1024,64]   vtb: [8,3072,1024] (transposed for PV B-operand)
// Gelu is STAGE-SPLIT (all-exp -> all-rcp -> all-fma) so pa[32]+ex[32] are
// simultaneously live -> forces wide VGPR allocation & parallel trans chains.
__global__ __launch_bounds__(256) __attribute__((amdgpu_waves_per_eu(2, 8)))
void conv_qkv_kernel(
    const float* __restrict__ x,
    const float* __restrict__ wq, const float* __restrict__ bq,
    const float* __restrict__ wk, const float* __restrict__ bk,
    const float* __restrict__ wv, const float* __restrict__ bv,
    unsigned short* __restrict__ qb, unsigned short* __restrict__ kb,
    unsigned short* __restrict__ vtb) {
  __shared__ float sin_[66][68];
  const int tid = threadIdx.x;
  const int b = blockIdx.z, g = blockIdx.y;
  const int s0 = blockIdx.x << 6;
  const float* xp = x + ((size_t)(b * 12 + g) << 16);
  for (int i = tid; i < 66 * 64; i += 256) {
    const int r = i >> 6, n = i & 63;
    const int s = s0 - 1 + r;
    sin_[r][n + 1] = (s >= 0 && s < 1024) ? xp[(s << 6) + n] : 0.0f;
  }
  if (tid < 66) { sin_[tid][0] = 0.0f; sin_[tid][65] = 0.0f; sin_[tid][66] = 0.0f; sin_[tid][67] = 0.0f; }
  __syncthreads();

  // ---- pass 1 (q & k): thread owns 4 rows x 4 cols; rolling 3-row window ----
  {
    const int n0 = (tid & 15) << 2;
    const int rb = (tid >> 4) << 2;
    float W[8][9], Bi[8];
#pragma unroll
    for (int j = 0; j < 4; ++j) {
      const int oc = (g << 2) + j;
#pragma unroll
      for (int t = 0; t < 9; ++t) { W[j][t] = wq[oc * 9 + t]; W[4 + j][t] = wk[oc * 9 + t]; }
      Bi[j] = bq[oc]; Bi[4 + j] = bk[oc];
    }
    float rA[6], rB[6], rC[6];
#define LDROW(dst, ridx)                                                              \
    { const float4 p0 = *reinterpret_cast<const float4*>(&sin_[ridx][n0]);            \
      const float2 p1 = *reinterpret_cast<const float2*>(&sin_[ridx][n0 + 4]);        \
      dst[0] = p0.x; dst[1] = p0.y; dst[2] = p0.z; dst[3] = p0.w;                     \
      dst[4] = p1.x; dst[5] = p1.y; }
    LDROW(rA, rb)
    LDROW(rB, rb + 1)
#pragma unroll
    for (int i = 0; i < 4; ++i) {
      const int s = rb + i;
      LDROW(rC, s + 2)
      float pa[8][4];
#pragma unroll
      for (int j = 0; j < 8; ++j)
#pragma unroll
        for (int q = 0; q < 4; ++q) {
          float a = Bi[j];
#pragma unroll
          for (int dc = 0; dc < 3; ++dc) {
            a = fmaf(W[j][dc], rA[q + dc], a);
            a = fmaf(W[j][3 + dc], rB[q + dc], a);
            a = fmaf(W[j][6 + dc], rC[q + dc], a);
          }
          pa[j][q] = a;
        }
      // stage-split gelu: 32 independent chains per stage
      float ex[8][4];
#pragma unroll
      for (int j = 0; j < 8; ++j)
#pragma unroll
        for (int q = 0; q < 4; ++q) {
          const float v = pa[j][q];
          ex[j][q] = exp2_raw(v * fmaf(0.10294373f, v * v, 2.3022077f));
        }
#pragma unroll
      for (int j = 0; j < 8; ++j)
#pragma unroll
        for (int q = 0; q < 4; ++q) ex[j][q] = __builtin_amdgcn_rcpf(ex[j][q] + 1.0f);
#pragma unroll
      for (int j = 0; j < 8; ++j)
#pragma unroll
        for (int q = 0; q < 4; ++q) pa[j][q] = fmaf(-pa[j][q], ex[j][q], pa[j][q]);
#pragma unroll
      for (int j = 0; j < 8; ++j) {
        const int oc = (g << 2) + (j & 3);
        unsigned short* dst = (j < 4) ? qb : kb;
        uint2 pk;
        pk.x = pk_bf16(pa[j][0], pa[j][1]);
        pk.y = pk_bf16(pa[j][2], pa[j][3]);
        *reinterpret_cast<uint2*>(dst + (((b * 48 + oc) << 16) + ((s0 + s) << 6) + n0)) = pk;
      }
#pragma unroll
      for (int c = 0; c < 6; ++c) { rA[c] = rB[c]; rB[c] = rC[c]; }
    }
#undef LDROW
  }

  // ---- pass 2 (v, transposed out): thread owns 2 rows (s-pair) x 8 cols ----
  {
    const int sp = (tid & 31) << 1;
    const int nb = (tid >> 5) << 3;
    float W[4][9], Bi[4];
#pragma unroll
    for (int j = 0; j < 4; ++j) {
      const int oc = (g << 2) + j;
#pragma unroll
      for (int t = 0; t < 9; ++t) W[j][t] = wv[oc * 9 + t];
      Bi[j] = bv[oc];
    }
    float c0[4], c1[4], c2[4];
#pragma unroll
    for (int r = 0; r < 4; ++r) { c0[r] = sin_[sp + r][nb]; c1[r] = sin_[sp + r][nb + 1]; }
#pragma unroll
    for (int i = 0; i < 8; ++i) {
      const int n = nb + i;
#pragma unroll
      for (int r = 0; r < 4; ++r) c2[r] = sin_[sp + r][n + 2];
      float pa[4][2];
#pragma unroll
      for (int j = 0; j < 4; ++j)
#pragma unroll
        for (int ss = 0; ss < 2; ++ss) {
          float a = Bi[j];
#pragma unroll
          for (int dr = 0; dr < 3; ++dr) {
            a = fmaf(W[j][dr * 3 + 0], c0[ss + dr], a);
            a = fmaf(W[j][dr * 3 + 1], c1[ss + dr], a);
            a = fmaf(W[j][dr * 3 + 2], c2[ss + dr], a);
          }
          pa[j][ss] = a;
        }
      float ex[4][2];
#pragma unroll
      for (int j = 0; j < 4; ++j)
#pragma unroll
        for (int ss = 0; ss < 2; ++ss) {
          const float v = pa[j][ss];
          ex[j][ss] = exp2_raw(v * fmaf(0.10294373f, v * v, 2.3022077f));
        }
#pragma unroll
      for (int j = 0; j < 4; ++j)
#pragma unroll
        for (int ss = 0; ss < 2; ++ss) ex[j][ss] = __builtin_amdgcn_rcpf(ex[j][ss] + 1.0f);
#pragma unroll
      for (int j = 0; j < 4; ++j)
#pragma unroll
        for (int ss = 0; ss < 2; ++ss) pa[j][ss] = fmaf(-pa[j][ss], ex[j][ss], pa[j][ss]);
#pragma unroll
      for (int j = 0; j < 4; ++j) {
        const size_t d = (size_t)b * 3072 + ((((g << 2) + j) << 6) + n);
        *reinterpret_cast<unsigned*>(vtb + ((d << 10) + s0 + sp)) = pk_bf16(pa[j][0], pa[j][1]);
      }
#pragma unroll
      for (int r = 0; r < 4; ++r) { c0[r] = c1[r]; c1[r] = c2[r]; }
    }
  }
}

// ---------- GEMM tile macros (shared by qk/pv) ----------
// LDS tile [128][64] bf16, XOR-swizzled col-blocks (T2, both-sides). T5 setprio
// wraps the compute cluster.
#define GEMM_COMPUTE(A_, B_) {                                                          \
    __builtin_amdgcn_s_setprio(1);                                                      \
    _Pragma("unroll")                                                                   \
    for (int kk = 0; kk < 2; ++kk) {                                                    \
      const int pos = ((((kk << 2) + lhi) ^ (l15 & 7)) << 3);                           \
      short8 aF[4], bF[4];                                                              \
      _Pragma("unroll")                                                                 \
      for (int m = 0; m < 4; ++m)                                                       \
        aF[m] = *reinterpret_cast<const short8*>(&(A_)[(((wm << 6) + (m << 4) + l15) << 6) + pos]); \
      _Pragma("unroll")                                                                 \
      for (int n = 0; n < 4; ++n)                                                       \
        bF[n] = *reinterpret_cast<const short8*>(&(B_)[(((wn << 6) + (n << 4) + l15) << 6) + pos]); \
      _Pragma("unroll")                                                                 \
      for (int m = 0; m < 4; ++m)                                                       \
        _Pragma("unroll")                                                               \
        for (int n = 0; n < 4; ++n)                                                     \
          acc[m][n] = __builtin_amdgcn_mfma_f32_16x16x32_bf16(aF[m], bF[n], acc[m][n], 0, 0, 0); \
    }                                                                                   \
    __builtin_amdgcn_s_setprio(0); }

// ---------- kernel 2: score = (Q K^T)/sqrt(768), fp32 out ----------
// q,k: [8,48,1024,64] bf16.  score: [8,1024,1024] f32.
// 2-phase prefetch (T3-min) + T2 swizzle; statically distinct double-buffers.
// (R10's counted-vmcnt 2-deep variant measured exactly 0 gain -> reverted.)
__global__ __launch_bounds__(256) void qk_kernel(
    const unsigned short* __restrict__ q, const unsigned short* __restrict__ k,
    float* __restrict__ score) {
  __shared__ __align__(16) unsigned short As0[128 * 64], As1[128 * 64];
  __shared__ __align__(16) unsigned short Bs0[128 * 64], Bs1[128 * 64];
  const int tid = threadIdx.x;
  const int w = tid >> 6, lane = tid & 63;
  const int b = blockIdx.z;
  const int s0 = blockIdx.y << 7, t0 = blockIdx.x << 7;
  const int wm = w >> 1, wn = w & 1;
  const int l15 = lane & 15, lhi = lane >> 4;
  const int srow = lane >> 3;           // row within 8-row stage group
  const int scb = (lane & 7) ^ srow;    // pre-swizzled source col-block
  f32x4 acc[4][4] = {};

  const unsigned short* qbase = q + ((b * 48) << 16) + (s0 << 6);
  const unsigned short* kbase = k + ((b * 48) << 16) + (t0 << 6);

#define QK_STAGE(cs, A_, B_) {                                        \
    const unsigned short* qa = qbase + ((cs) << 16);                  \
    const unsigned short* ka = kbase + ((cs) << 16);                  \
    _Pragma("unroll")                                                 \
    for (int i = 0; i < 4; ++i) {                                     \
      const int fe = ((((i * 4 + w) << 3) + srow) << 6) + (scb << 3); \
      const int lb = (i * 4 + w) << 10;                               \
      gload16(qa + fe, (char*)(A_) + lb);                             \
      gload16(ka + fe, (char*)(B_) + lb);                             \
    } }

  QK_STAGE(0, As0, Bs0)
  DRAIN_BAR
  for (int c2 = 0; c2 < 24; ++c2) {
    const int c0 = c2 << 1;
    QK_STAGE(c0 + 1, As1, Bs1)
    GEMM_COMPUTE(As0, Bs0)
    DRAIN_BAR
    if (c0 + 2 < 48) QK_STAGE(c0 + 2, As0, Bs0)
    GEMM_COMPUTE(As1, Bs1)
    DRAIN_BAR
  }
#undef QK_STAGE
  const float scale = 0.03608439182435161f;  // 1/sqrt(768)
#pragma unroll
  for (int m = 0; m < 4; ++m) {
    const int row = (wm << 6) + (m << 4) + (lhi << 2);
#pragma unroll
    for (int n = 0; n < 4; ++n) {
      const int col = (wn << 6) + (n << 4) + l15;
      float* op = score + ((size_t)((b << 10) + s0 + row) << 10) + t0 + col;
#pragma unroll
      for (int r = 0; r < 4; ++r) op[(size_t)r << 10] = acc[m][n][r] * scale;
    }
  }
}

// ---------- kernel 3: row softmax, fp32 in, bf16 out ----------
__global__ __launch_bounds__(256) void softmax_kernel(
    const float* __restrict__ score, unsigned short* __restrict__ p) {
  __shared__ float redm[4], reds[4];
  const int row = blockIdx.x;
  const int tid = threadIdx.x;
  const int w = tid >> 6, lane = tid & 63;
  const float* sr = score + ((size_t)row << 10);
  const float4 v = reinterpret_cast<const float4*>(sr)[tid];
  float mx = fmaxf(fmaxf(v.x, v.y), fmaxf(v.z, v.w));
#pragma unroll
  for (int o = 1; o < 64; o <<= 1) mx = fmaxf(mx, __shfl_xor(mx, o));
  if (lane == 0) redm[w] = mx;
  __syncthreads();
  mx = fmaxf(fmaxf(redm[0], redm[1]), fmaxf(redm[2], redm[3]));
  const float e0 = __expf(v.x - mx), e1 = __expf(v.y - mx);
  const float e2 = __expf(v.z - mx), e3 = __expf(v.w - mx);
  float s = e0 + e1 + e2 + e3;
#pragma unroll
  for (int o = 1; o < 64; o <<= 1) s += __shfl_xor(s, o);
  if (lane == 0) reds[w] = s;
  __syncthreads();
  s = reds[0] + reds[1] + reds[2] + reds[3];
  const float inv = 1.0f / s;
  uint2 pk;
  pk.x = pk_bf16(e0 * inv, e1 * inv);
  pk.y = pk_bf16(e2 * inv, e3 * inv);
  *reinterpret_cast<uint2*>(&p[((size_t)row << 10) + (tid << 2)]) = pk;
}

// ---------- kernel 4: O = P @ V2  (per batch 1024x3072x1024) ----------
// p: [8,1024,1024] bf16; vt: [8,3072,1024] bf16; o2: [8,1024,3072] bf16
// 2-phase prefetch + T2 swizzle, grid (24,8,8)
__global__ __launch_bounds__(256) void pv_kernel(
    const unsigned short* __restrict__ p, const unsigned short* __restrict__ vt,
    unsigned short* __restrict__ o2) {
  __shared__ __align__(16) unsigned short As0[128 * 64], As1[128 * 64];
  __shared__ __align__(16) unsigned short Bs0[128 * 64], Bs1[128 * 64];
  const int tid = threadIdx.x;
  const int w = tid >> 6, lane = tid & 63;
  const int b = blockIdx.z;
  const int s0 = blockIdx.y << 7, d0 = blockIdx.x << 7;
  const int wm = w >> 1, wn = w & 1;
  const int l15 = lane & 15, lhi = lane >> 4;
  const int srow = lane >> 3;
  const int scb = (lane & 7) ^ srow;
  f32x4 acc[4][4] = {};

  const unsigned short* pbase = p + ((size_t)(b << 10) << 10);
  const unsigned short* vbase = vt + ((size_t)(b * 3072 + d0) << 10);

#define PV_STAGE(t0k, A_, B_) {                                          \
    _Pragma("unroll")                                                    \
    for (int i = 0; i < 4; ++i) {                                        \
      const int rr = ((i * 4 + w) << 3) + srow;                          \
      const int cc = (t0k) + (scb << 3);                                 \
      const int lb = (i * 4 + w) << 10;                                  \
      gload16(pbase + ((size_t)(s0 + rr) << 10) + cc, (char*)(A_) + lb); \
      gload16(vbase + ((size_t)rr << 10) + cc, (char*)(B_) + lb);        \
    } }

  PV_STAGE(0, As0, Bs0)
  DRAIN_BAR
  for (int t2 = 0; t2 < 8; ++t2) {
    const int t0k = t2 << 7;
    PV_STAGE(t0k + 64, As1, Bs1)
    GEMM_COMPUTE(As0, Bs0)
    DRAIN_BAR
    if (t0k + 128 < 1024) PV_STAGE(t0k + 128, As0, Bs0)
    GEMM_COMPUTE(As1, Bs1)
    DRAIN_BAR
  }
#undef PV_STAGE
#pragma unroll
  for (int m = 0; m < 4; ++m) {
    const int row = (wm << 6) + (m << 4) + (lhi << 2);
#pragma unroll
    for (int n = 0; n < 4; ++n) {
      const int col = (wn << 6) + (n << 4) + l15;
      unsigned short* op = o2 + ((size_t)((b << 10) + s0 + row)) * 3072 + d0 + col;
#pragma unroll
      for (int r = 0; r < 4; ++r) op[(size_t)r * 3072] = f2bf(acc[m][n][r]);
    }
  }
}

// ---------- kernel 5: 1x1 conv (48->12) + LayerNorm(64) + residual ----------
__global__ __launch_bounds__(256) void out_kernel(
    const unsigned short* __restrict__ o2, const float* __restrict__ x,
    const float* __restrict__ w1, const float* __restrict__ b1,
    const float* __restrict__ lnw, const float* __restrict__ lnb,
    float* __restrict__ out) {
  const int tid = threadIdx.x;
  const int w = tid >> 6, lane = tid & 63;
  const int row = (blockIdx.x << 2) + w;      // b*1024 + s
  const int b = row >> 10, s = row & 1023;
  const unsigned short* op = o2 + (size_t)row * 3072 + lane;
  float ov[48];
#pragma unroll
  for (int c = 0; c < 48; ++c) ov[c] = bf2f(op[c << 6]);
  float acc[12];
#pragma unroll
  for (int m = 0; m < 12; ++m) {
    float a = b1[m];
#pragma unroll
    for (int c = 0; c < 48; ++c) a = fmaf(ov[c], w1[m * 48 + c], a);
    acc[m] = a;
  }
  const float wn_ = lnw[lane], bn_ = lnb[lane];
#pragma unroll
  for (int m = 0; m < 12; ++m) {
    float s1 = acc[m], s2 = acc[m] * acc[m];
#pragma unroll
    for (int o = 1; o < 64; o <<= 1) { s1 += __shfl_xor(s1, o); s2 += __shfl_xor(s2, o); }
    const float mu = s1 * 0.015625f;
    const float var = s2 * 0.015625f - mu * mu;
    const float rs = rsqrtf(var + 1e-5f);
    const size_t xi = ((size_t)(b * 12 + m) << 16) + (s << 6) + lane;
    out[xi] = (acc[m] - mu) * rs * wn_ + bn_ + x[xi];
  }
}

// ---------- launch ----------
extern "C" void kernel_launch(void* const* d_in, const int* in_sizes, int n_in,
                              void* d_out, int out_size, void* d_ws, size_t ws_size,
                              hipStream_t stream) {
  (void)in_sizes; (void)n_in; (void)out_size; (void)ws_size;
  const float* x   = (const float*)d_in[0];
  const float* wq  = (const float*)d_in[1];
  const float* bq  = (const float*)d_in[2];
  const float* wk  = (const float*)d_in[3];
  const float* bk  = (const float*)d_in[4];
  const float* wv  = (const float*)d_in[5];
  const float* bv  = (const float*)d_in[6];
  const float* w1  = (const float*)d_in[7];
  const float* b1  = (const float*)d_in[8];
  const float* lnw = (const float*)d_in[9];
  const float* lnb = (const float*)d_in[10];

  char* ws = (char*)d_ws;
  unsigned short* qb  = (unsigned short*)(ws);              // 50331648 B
  unsigned short* kb  = (unsigned short*)(ws + 50331648);   // 50331648 B
  unsigned short* vtb = (unsigned short*)(ws + 100663296);  // 50331648 B
  float*          sc  = (float*)(ws + 150994944);           // 33554432 B
  unsigned short* pb  = (unsigned short*)(ws + 184549376);  // 16777216 B  (total 192 MiB)
  unsigned short* o2b = (unsigned short*)(ws);              // reuse q region (dead after qk)
  float* outp = (float*)d_out;

  conv_qkv_kernel<<<dim3(16, 12, 8), 256, 0, stream>>>(x, wq, bq, wk, bk, wv, bv, qb, kb, vtb);
  qk_kernel<<<dim3(8, 8, 8), 256, 0, stream>>>(qb, kb, sc);
  softmax_kernel<<<dim3(8192), 256, 0, stream>>>(sc, pb);
  pv_kernel<<<dim3(24, 8, 8), 256, 0, stream>>>(pb, vtb, o2b);
  out_kernel<<<dim3(2048), 256, 0, stream>>>(o2b, x, w1, b1, lnw, lnb, outp);
}